// Round 1
// baseline (245.214 us; speedup 1.0000x reference)
//
#include <hip/hip_runtime.h>

// ---------------------------------------------------------------------------
// MultiHeadAttention forward, MI355X/gfx950.
// Pipeline: convert(f32->bf16) -> GEMM Q/K/V proj -> flash attention -> GEMM O proj
// ---------------------------------------------------------------------------

typedef short bf16x8 __attribute__((ext_vector_type(8)));
typedef float f32x4 __attribute__((ext_vector_type(4)));
typedef unsigned short u16;
typedef unsigned short u16x8 __attribute__((ext_vector_type(8)));
typedef unsigned short u16x4 __attribute__((ext_vector_type(4)));

#define MFMA16(a, b, c) __builtin_amdgcn_mfma_f32_16x16x32_bf16((a), (b), (c), 0, 0, 0)
#define GLD16(gp, lp)                                                     \
  __builtin_amdgcn_global_load_lds(                                       \
      (const __attribute__((address_space(1))) void*)(gp),                \
      (__attribute__((address_space(3))) void*)(lp), 16, 0, 0)

__device__ __forceinline__ u16 f2bf(float f) {
  union { float f; unsigned u; } v; v.f = f;
  return (u16)((v.u + 0x7fffu + ((v.u >> 16) & 1u)) >> 16);
}

// ---------------- f32 -> bf16 conversion (7 arrays in one launch) ----------
struct ConvDesc { const float* src; u16* dst; int n; };
struct ConvArgs { ConvDesc d[7]; };

__global__ __launch_bounds__(256) void k_convert(ConvArgs a) {
  ConvDesc cd = a.d[blockIdx.y];
  int i = (blockIdx.x * 256 + threadIdx.x) * 8;
  if (i >= cd.n) return;
  const float4* s = (const float4*)(cd.src + i);
  float4 f0 = s[0], f1 = s[1];
  u16x8 o;
  o[0] = f2bf(f0.x); o[1] = f2bf(f0.y); o[2] = f2bf(f0.z); o[3] = f2bf(f0.w);
  o[4] = f2bf(f1.x); o[5] = f2bf(f1.y); o[6] = f2bf(f1.z); o[7] = f2bf(f1.w);
  *(u16x8*)(cd.dst + i) = o;
}

// ---------------- bf16 GEMM: C[M,N] = A[M,K] * B[N,K]^T + bias ------------
// M=4096, N=1024, K=1024. 128x128 tile, BK=32, 4 waves (2x2), 16x16x32 MFMA.
// mode 0: out bf16 [B,H,N,64]   (Q,K heads layout)
// mode 1: out bf16 [B,H,64,N]   (V transposed)
// mode 2: out f32  [M,1024]     (final projection to d_out)
__global__ __launch_bounds__(256, 2)
void k_gemm_bt(const u16* __restrict__ A, const u16* __restrict__ Bw,
               const float* __restrict__ bias, void* __restrict__ outp,
               int mode) {
  __shared__ u16 As[128 * 32];
  __shared__ u16 Bs[128 * 32];
  const int tid = threadIdx.x;
  const int lane = tid & 63;
  const int wv = tid >> 6;
  const int wr = wv >> 1, wc = wv & 1;
  const int m0 = blockIdx.y * 128, n0 = blockIdx.x * 128;

  f32x4 acc[4][4] = {};

  // staging map: s = i*256+tid, row = s>>2 (64B rows, 4 chunks), chunk xor (row&3)
  const int s0 = tid, s1 = 256 + tid;
  const int r0 = s0 >> 2, c0 = (s0 & 3) ^ (r0 & 3);
  const int r1 = s1 >> 2, c1 = (s1 & 3) ^ (r1 & 3);
  const u16* gA0 = A + (size_t)(m0 + r0) * 1024 + c0 * 8;
  const u16* gA1 = A + (size_t)(m0 + r1) * 1024 + c1 * 8;
  const u16* gB0 = Bw + (size_t)(n0 + r0) * 1024 + c0 * 8;
  const u16* gB1 = Bw + (size_t)(n0 + r1) * 1024 + c1 * 8;
  u16* lA0 = As + (tid & ~63) * 8;
  u16* lA1 = As + (256 + (tid & ~63)) * 8;
  u16* lB0 = Bs + (tid & ~63) * 8;
  u16* lB1 = Bs + (256 + (tid & ~63)) * 8;

  for (int k0 = 0; k0 < 1024; k0 += 32) {
    GLD16(gA0 + k0, lA0);
    GLD16(gA1 + k0, lA1);
    GLD16(gB0 + k0, lB0);
    GLD16(gB1 + k0, lB1);
    __syncthreads();  // compiler drains vmcnt before barrier
    bf16x8 af[4], bfr[4];
#pragma unroll
    for (int mi = 0; mi < 4; mi++) {
      int row = wr * 64 + mi * 16 + (lane & 15);
      int byt = row * 64 + (((lane >> 4) * 16) ^ ((row & 3) << 4));
      af[mi] = *(const bf16x8*)((const char*)As + byt);
    }
#pragma unroll
    for (int ni = 0; ni < 4; ni++) {
      int row = wc * 64 + ni * 16 + (lane & 15);
      int byt = row * 64 + (((lane >> 4) * 16) ^ ((row & 3) << 4));
      bfr[ni] = *(const bf16x8*)((const char*)Bs + byt);
    }
#pragma unroll
    for (int mi = 0; mi < 4; mi++)
#pragma unroll
      for (int ni = 0; ni < 4; ni++)
        acc[mi][ni] = MFMA16(af[mi], bfr[ni], acc[mi][ni]);
    __syncthreads();
  }

  // epilogue: C/D layout col = lane&15, row = (lane>>4)*4 + r
#pragma unroll
  for (int ni = 0; ni < 4; ni++) {
    int n = n0 + wc * 64 + ni * 16 + (lane & 15);
    float bv = bias[n];
#pragma unroll
    for (int mi = 0; mi < 4; mi++) {
      int mb = m0 + wr * 64 + mi * 16 + (lane >> 4) * 4;
      if (mode == 2) {
        float* O = (float*)outp;
#pragma unroll
        for (int r = 0; r < 4; r++)
          O[(size_t)(mb + r) * 1024 + n] = acc[mi][ni][r] + bv;
      } else if (mode == 0) {
        u16* O = (u16*)outp;
        int b = mb >> 11, q = mb & 2047;
        int h = n >> 6, dk = n & 63;
        size_t base = ((size_t)(b * 16 + h) * 2048 + q) * 64 + dk;
#pragma unroll
        for (int r = 0; r < 4; r++)
          O[base + (size_t)r * 64] = f2bf(acc[mi][ni][r] + bv);
      } else {  // mode 1: V^T [B,H,64,NK]
        u16* O = (u16*)outp;
        int b = mb >> 11, kv = mb & 2047;
        int h = n >> 6, dk = n & 63;
        u16x4 pk;
#pragma unroll
        for (int r = 0; r < 4; r++) pk[r] = f2bf(acc[mi][ni][r] + bv);
        *(u16x4*)((u16*)O + ((size_t)((b * 16 + h) * 64 + dk)) * 2048 + kv) = pk;
      }
    }
  }
}

// ---------------- flash attention ------------------------------------------
// grid (h=16, qt=32, b=2), 256 threads. Wave w owns q rows q0+w*16..+15.
// K,V tiles (64 kv x 64 dk / 64 dk x 64 kv) staged via global_load_lds with
// XOR swizzle (linear dest, pre-swizzled source). Online softmax in f32.
__global__ __launch_bounds__(256, 2)
void k_attn(const u16* __restrict__ Qb, const u16* __restrict__ Kb,
            const u16* __restrict__ Vt, const float* __restrict__ bias,
            const int* __restrict__ mask, u16* __restrict__ Ob) {
  __shared__ u16 Ks[64 * 64];
  __shared__ u16 Vs[64 * 64];
  __shared__ u16 Ps[4][16 * 88];  // per-wave P transpose buffer, stride 88 (176B, 16B-aligned)

  const int tid = threadIdx.x, lane = tid & 63, w = tid >> 6;
  const int h = blockIdx.x, qt = blockIdx.y, b = blockIdx.z;
  const int q0 = qt * 64;
  const size_t bh = (size_t)(b * 16 + h);

  // Q fragments (held all kernel): A-frag row = lane&15, k = (lane>>4)*8 + ch*32
  const u16* Qrow = Qb + (bh * 2048 + q0 + w * 16 + (lane & 15)) * 64;
  bf16x8 aq[2];
  aq[0] = *(const bf16x8*)(Qrow + (lane >> 4) * 8);
  aq[1] = *(const bf16x8*)(Qrow + 32 + (lane >> 4) * 8);

  f32x4 acc_o[4] = {};
  float mrun[4] = {-1e30f, -1e30f, -1e30f, -1e30f};
  float lrun[4] = {0.f, 0.f, 0.f, 0.f};

  // staging map: s = i*256+tid, row = s>>3 (128B rows, 8 chunks), chunk xor (row&7)
  const int sA = tid, sB = 256 + tid;
  const int rK0 = sA >> 3, cK0 = (sA & 7) ^ (rK0 & 7);
  const int rK1 = sB >> 3, cK1 = (sB & 7) ^ (rK1 & 7);
  const u16* Kbase = Kb + bh * 2048 * 64;
  const u16* Vbase = Vt + bh * 64 * 2048;
  u16* lK0 = Ks + (tid & ~63) * 8;
  u16* lK1 = Ks + (256 + (tid & ~63)) * 8;
  u16* lV0 = Vs + (tid & ~63) * 8;
  u16* lV1 = Vs + (256 + (tid & ~63)) * 8;

  const float* biasrow[4];
#pragma unroll
  for (int r = 0; r < 4; r++)
    biasrow[r] =
        bias + ((size_t)b * 2048 + q0 + w * 16 + (lane >> 4) * 4 + r) * 2048;
  const int* maskrow = mask + b * 2048;

  for (int t = 0; t < 32; t++) {
    const int kv0 = t * 64;
    GLD16(Kbase + (size_t)(kv0 + rK0) * 64 + cK0 * 8, lK0);
    GLD16(Kbase + (size_t)(kv0 + rK1) * 64 + cK1 * 8, lK1);
    GLD16(Vbase + (size_t)rK0 * 2048 + kv0 + cK0 * 8, lV0);
    GLD16(Vbase + (size_t)rK1 * 2048 + kv0 + cK1 * 8, lV1);
    __syncthreads();

    // S = Q*K^T for 4 kv col-tiles
    f32x4 sc[4];
#pragma unroll
    for (int c = 0; c < 4; c++) {
      f32x4 z = {};
#pragma unroll
      for (int ch = 0; ch < 2; ch++) {
        int kvr = c * 16 + (lane & 15);
        int koffb = (ch * 32 + (lane >> 4) * 8) * 2;
        bf16x8 bk =
            *(const bf16x8*)((const char*)Ks + kvr * 128 + (koffb ^ ((kvr & 7) << 4)));
        z = MFMA16(aq[ch], bk, z);
      }
      sc[c] = z;
    }

    // scale + bias + mask
    int mk[4];
#pragma unroll
    for (int c = 0; c < 4; c++) mk[c] = maskrow[kv0 + c * 16 + (lane & 15)];
    float pv[4][4];
    float tmax[4] = {-1e30f, -1e30f, -1e30f, -1e30f};
#pragma unroll
    for (int c = 0; c < 4; c++) {
#pragma unroll
      for (int r = 0; r < 4; r++) {
        float s = sc[c][r] * 0.125f + biasrow[r][kv0 + c * 16 + (lane & 15)];
        s = (mk[c] == 0) ? -1e9f : s;
        pv[c][r] = s;
        tmax[r] = fmaxf(tmax[r], s);
      }
    }
    // row max over the 16-lane group
#pragma unroll
    for (int off = 1; off < 16; off <<= 1)
#pragma unroll
      for (int r = 0; r < 4; r++)
        tmax[r] = fmaxf(tmax[r], __shfl_xor(tmax[r], off, 64));

    float alpha[4];
#pragma unroll
    for (int r = 0; r < 4; r++) {
      float mnew = fmaxf(mrun[r], tmax[r]);
      alpha[r] = __expf(mrun[r] - mnew);
      mrun[r] = mnew;
    }
#pragma unroll
    for (int c = 0; c < 4; c++)
#pragma unroll
      for (int r = 0; r < 4; r++) pv[c][r] = __expf(pv[c][r] - mrun[r]);

    float rsum[4];
#pragma unroll
    for (int r = 0; r < 4; r++)
      rsum[r] = (pv[0][r] + pv[1][r]) + (pv[2][r] + pv[3][r]);
#pragma unroll
    for (int off = 1; off < 16; off <<= 1)
#pragma unroll
      for (int r = 0; r < 4; r++) rsum[r] += __shfl_xor(rsum[r], off, 64);
#pragma unroll
    for (int r = 0; r < 4; r++) lrun[r] = lrun[r] * alpha[r] + rsum[r];

    // rescale O
#pragma unroll
    for (int d = 0; d < 4; d++)
#pragma unroll
      for (int r = 0; r < 4; r++) acc_o[d][r] *= alpha[r];

    // P -> per-wave LDS (bf16), transposed read as MFMA A-operand
    u16* Pw = Ps[w];
#pragma unroll
    for (int c = 0; c < 4; c++)
#pragma unroll
      for (int r = 0; r < 4; r++)
        Pw[((lane >> 4) * 4 + r) * 88 + c * 16 + (lane & 15)] = f2bf(pv[c][r]);

    // O += P * V
#pragma unroll
    for (int ch = 0; ch < 2; ch++) {
      bf16x8 pa = *(const bf16x8*)((const char*)Pw + (lane & 15) * 176 +
                                   (ch * 32 + (lane >> 4) * 8) * 2);
#pragma unroll
      for (int d = 0; d < 4; d++) {
        int dr = d * 16 + (lane & 15);
        int koffb = (ch * 32 + (lane >> 4) * 8) * 2;
        bf16x8 vb =
            *(const bf16x8*)((const char*)Vs + dr * 128 + (koffb ^ ((dr & 7) << 4)));
        acc_o[d] = MFMA16(pa, vb, acc_o[d]);
      }
    }
    __syncthreads();
  }

  // write O (bf16, [B, NQ, H*64])
#pragma unroll
  for (int d = 0; d < 4; d++) {
#pragma unroll
    for (int r = 0; r < 4; r++) {
      int q = q0 + w * 16 + (lane >> 4) * 4 + r;
      float v = acc_o[d][r] / lrun[r];
      Ob[((size_t)b * 2048 + q) * 1024 + h * 64 + d * 16 + (lane & 15)] = f2bf(v);
    }
  }
}

// ---------------------------------------------------------------------------
extern "C" void kernel_launch(void* const* d_in, const int* in_sizes, int n_in,
                              void* d_out, int out_size, void* d_ws,
                              size_t ws_size, hipStream_t stream) {
  (void)in_sizes; (void)n_in; (void)out_size; (void)ws_size;
  const float* q_in = (const float*)d_in[0];
  const float* k_in = (const float*)d_in[1];
  const float* v_in = (const float*)d_in[2];
  const int* mask = (const int*)d_in[3];
  const float* attn_bias = (const float*)d_in[4];
  const float* w_q = (const float*)d_in[5];
  const float* b_q = (const float*)d_in[6];
  const float* w_k = (const float*)d_in[7];
  const float* b_k = (const float*)d_in[8];
  const float* w_v = (const float*)d_in[9];
  const float* b_v = (const float*)d_in[10];
  const float* w_o = (const float*)d_in[11];
  const float* b_o = (const float*)d_in[12];

  const size_t MB = 1u << 20;
  char* ws = (char*)d_ws;
  u16* XQ = (u16*)(ws + 0 * MB);
  u16* XK = (u16*)(ws + 8 * MB);
  u16* XV = (u16*)(ws + 16 * MB);
  u16* WQ = (u16*)(ws + 24 * MB);
  u16* WK = (u16*)(ws + 26 * MB);
  u16* WV = (u16*)(ws + 28 * MB);
  u16* WO = (u16*)(ws + 30 * MB);
  u16* Qb = (u16*)(ws + 32 * MB);
  u16* Kb = (u16*)(ws + 40 * MB);
  u16* Vt = (u16*)(ws + 48 * MB);
  u16* Ob = (u16*)(ws + 56 * MB);

  ConvArgs ca;
  ca.d[0] = {q_in, XQ, 4096 * 1024};
  ca.d[1] = {k_in, XK, 4096 * 1024};
  ca.d[2] = {v_in, XV, 4096 * 1024};
  ca.d[3] = {w_q, WQ, 1024 * 1024};
  ca.d[4] = {w_k, WK, 1024 * 1024};
  ca.d[5] = {w_v, WV, 1024 * 1024};
  ca.d[6] = {w_o, WO, 1024 * 1024};
  k_convert<<<dim3(2048, 7), 256, 0, stream>>>(ca);

  dim3 ggrid(8, 32);  // N/128, M/128
  k_gemm_bt<<<ggrid, 256, 0, stream>>>(XQ, WQ, b_q, (void*)Qb, 0);
  k_gemm_bt<<<ggrid, 256, 0, stream>>>(XK, WK, b_k, (void*)Kb, 0);
  k_gemm_bt<<<ggrid, 256, 0, stream>>>(XV, WV, b_v, (void*)Vt, 1);

  k_attn<<<dim3(16, 32, 2), 256, 0, stream>>>(Qb, Kb, Vt, attn_bias, mask, Ob);

  k_gemm_bt<<<ggrid, 256, 0, stream>>>(Ob, WO, b_o, d_out, 2);
}